// Round 1
// baseline (671.836 us; speedup 1.0000x reference)
//
#include <hip/hip_runtime.h>
#include <math.h>

// EfficientDet postprocess for MI355X.
// Pipeline: anchors -> decode -> sigmoid+transpose -> per-(b,c) topk+NMS (tier1
// prefix=rank1536, exact fallback rank5000) -> per-batch stable top-100 combine.

#define NANCH 49104
#define NB 8
#define NC 90
#define NBC 720
#define POSTN 100

// ---------- exact-float helpers (mirror numpy f32 semantics, no FMA) ----------

__device__ __forceinline__ float sigmoid_ref(float x) {
  if (x >= 0.0f) return __fdiv_rn(1.0f, __fadd_rn(1.0f, expf(-x)));
  float e = expf(x);
  return __fdiv_rn(e, __fadd_rn(1.0f, e));
}

__device__ __forceinline__ float iou_ref(float4 a, float4 b) {
  float yy1 = fmaxf(a.x, b.x);
  float xx1 = fmaxf(a.y, b.y);
  float yy2 = fminf(a.z, b.z);
  float xx2 = fminf(a.w, b.w);
  float ih = fmaxf(__fsub_rn(yy2, yy1), 0.0f);
  float iw = fmaxf(__fsub_rn(xx2, xx1), 0.0f);
  float inter = __fmul_rn(ih, iw);
  float a1 = __fmul_rn(__fsub_rn(a.z, a.x), __fsub_rn(a.w, a.y));
  float a2 = __fmul_rn(__fsub_rn(b.z, b.x), __fsub_rn(b.w, b.y));
  float den = __fadd_rn(__fsub_rn(__fadd_rn(a1, a2), inter), 1e-8f);
  return __fdiv_rn(inter, den);
}

// ---------------------------- anchors -----------------------------------------

__global__ __launch_bounds__(256) void k_anchors(float4* __restrict__ anchors) {
  int n = blockIdx.x * 256 + threadIdx.x;
  if (n >= NANCH) return;
  int l, off;
  if (n < 36864)      { l = 0; off = 0; }
  else if (n < 46080) { l = 1; off = 36864; }
  else if (n < 48384) { l = 2; off = 46080; }
  else if (n < 48960) { l = 3; off = 48384; }
  else                { l = 4; off = 48960; }
  int stride = 8 << l;
  int feat = 64 >> l;
  int r = n - off;
  int cell = r / 9, a = r - cell * 9;
  int iy = cell / feat, ix = cell - iy * feat;
  int isc = a / 3, ir = a - isc * 3;
  // numpy computes half-sizes in float64, then casts to float32
  double base = exp2((double)isc / 3.0) * (double)stride * 4.0;
  double rt = (ir == 0) ? 1.0 : (ir == 1 ? 0.5 : 2.0);
  double sq = sqrt(rt);
  float hh = (float)(base / sq / 2.0);
  float hw = (float)(base * sq / 2.0);
  float cy = __fmul_rn(__fadd_rn((float)iy, 0.5f), (float)stride);
  float cx = __fmul_rn(__fadd_rn((float)ix, 0.5f), (float)stride);
  anchors[n] = make_float4(__fsub_rn(cy, hh), __fsub_rn(cx, hw),
                           __fadd_rn(cy, hh), __fadd_rn(cx, hw));
}

// ---------------------------- decode -------------------------------------------

__global__ __launch_bounds__(256) void k_decode(const float4* __restrict__ deltas,
                                                const float4* __restrict__ anchors,
                                                float4* __restrict__ boxes) {
  int i = blockIdx.x * 256 + threadIdx.x;
  if (i >= NB * NANCH) return;
  int n = i % NANCH;
  float4 a = anchors[n];
  float4 d = deltas[i];
  float ah = __fsub_rn(a.z, a.x);
  float aw = __fsub_rn(a.w, a.y);
  float acy = __fmul_rn(__fadd_rn(a.x, a.z), 0.5f);
  float acx = __fmul_rn(__fadd_rn(a.y, a.w), 0.5f);
  float cy = __fadd_rn(__fmul_rn(d.x, ah), acy);
  float cx = __fadd_rn(__fmul_rn(d.y, aw), acx);
  float h = __fmul_rn(expf(d.z), ah);
  float w = __fmul_rn(expf(d.w), aw);
  float y1 = __fsub_rn(cy, __fmul_rn(h, 0.5f));
  float x1 = __fsub_rn(cx, __fmul_rn(w, 0.5f));
  float y2 = __fadd_rn(cy, __fmul_rn(h, 0.5f));
  float x2 = __fadd_rn(cx, __fmul_rn(w, 0.5f));
  const float inv = 0.001953125f;  // 1/512, exact
  y1 = fminf(fmaxf(__fmul_rn(y1, inv), 0.0f), 1.0f);
  x1 = fminf(fmaxf(__fmul_rn(x1, inv), 0.0f), 1.0f);
  y2 = fminf(fmaxf(__fmul_rn(y2, inv), 0.0f), 1.0f);
  x2 = fminf(fmaxf(__fmul_rn(x2, inv), 0.0f), 1.0f);
  boxes[i] = make_float4(y1, x1, y2, x2);
}

// ---------------------- sigmoid + transpose [B,N,C] -> [B,C,N] -----------------

__global__ __launch_bounds__(256) void k_trans(const float* __restrict__ logits,
                                               float* __restrict__ sT) {
  int tile = blockIdx.x;
  int b = blockIdx.y;
  __shared__ float t[64 * 91];  // +1 col pad breaks bank conflicts
  int n0 = tile * 64;
  int rows = min(64, NANCH - n0);
  for (int e = threadIdx.x; e < rows * 90; e += 256) {
    int r = e / 90, c = e - r * 90;
    float x = logits[((size_t)(b * NANCH + n0 + r)) * 90 + c];
    t[r * 91 + c] = sigmoid_ref(x);
  }
  __syncthreads();
  for (int e = threadIdx.x; e < 90 * 64; e += 256) {
    int c = e / 64, r = e - c * 64;
    if (r < rows)
      sT[((size_t)(b * 90 + c)) * NANCH + n0 + r] = t[r * 91 + c];
  }
}

// ---------------------- per-(b,c) topk + greedy NMS -----------------------------
// Tier1: CAP=2048, RANK=1536 (flags on exhaust/overflow). Fallback: CAP=8192,
// RANK=5000 (exact reference semantics incl. stable rank-5000 tie truncation).

template <int CAP, int RANK, bool FB>
__global__ __launch_bounds__(256) void k_nms(const float* __restrict__ sT,
                                             const float* __restrict__ logits,
                                             const float4* __restrict__ boxes,
                                             float* __restrict__ sel_s,
                                             float4* __restrict__ sel_b,
                                             int* __restrict__ flags, int use_T) {
  int bc = blockIdx.x;
  if (FB && flags[bc] == 0) return;
  int b = bc / NC;
  int c = bc - b * NC;
  int tid = threadIdx.x;

  __shared__ unsigned int s_key[CAP];
  __shared__ unsigned short s_idx[CAP];
  __shared__ __align__(16) unsigned char s_pool[8192];  // hist(2048 u32) then cbox(512 f4)
  __shared__ unsigned int s_bsum[256];
  __shared__ unsigned char s_alive[512];
  __shared__ float4 s_selbox[POSTN];
  __shared__ float s_sels[POSTN];
  __shared__ int s_cnt, s_nsel, s_cutbin;

  const float* srow = sT + (size_t)bc * NANCH;
  const float* lrow = logits + (size_t)b * NANCH * 90 + c;

  unsigned int* hist = (unsigned int*)s_pool;
  for (int e = tid; e < 2048; e += 256) hist[e] = 0u;
  if (tid == 0) { s_cnt = 0; s_nsel = 0; s_cutbin = 0; }
  __syncthreads();

  // pass 1: value-binned histogram. bin = floor(s*2048) is EXACT (pow2 scale),
  // so hist bins and the gather predicate (s >= bin/2048) are consistent.
  for (int n = tid; n < NANCH; n += 256) {
    float s = use_T ? srow[n] : sigmoid_ref(lrow[(size_t)n * 90]);
    int bin = (int)(s * 2048.0f);
    if (bin > 2047) bin = 2047;
    atomicAdd(&hist[bin], 1u);
  }
  __syncthreads();
  unsigned int loc = 0;
#pragma unroll
  for (int k = 0; k < 8; k++) loc += hist[tid * 8 + k];
  s_bsum[tid] = loc;
  __syncthreads();
  if (tid == 0) {
    unsigned int cum = 0;
    int bin = 0;
    bool fnd = false;
    for (int t = 255; t >= 0 && !fnd; t--) {
      if (cum + s_bsum[t] >= (unsigned)RANK) {
        for (int kk = 7; kk >= 0; kk--) {
          unsigned int h = hist[t * 8 + kk];
          if (cum + h >= (unsigned)RANK) { bin = t * 8 + kk; fnd = true; break; }
          cum += h;
        }
      } else {
        cum += s_bsum[t];
      }
    }
    s_cutbin = bin;
  }
  __syncthreads();
  float edge = __fmul_rn((float)s_cutbin, (1.0f / 2048.0f));  // exact

  // pass 2: gather all candidates >= edge (order canonicalized by sort below)
  for (int n = tid; n < NANCH; n += 256) {
    float s = use_T ? srow[n] : sigmoid_ref(lrow[(size_t)n * 90]);
    if (s >= edge) {
      int pos = atomicAdd(&s_cnt, 1);
      if (pos < CAP) {
        s_key[pos] = __float_as_uint(s);  // s>0 -> positive-float bit order
        s_idx[pos] = (unsigned short)n;
      }
    }
  }
  __syncthreads();
  int M = s_cnt;
  bool overflow = (M > CAP);
  if (M > CAP) M = CAP;
  for (int e = M + tid; e < CAP; e += 256) { s_key[e] = 0u; s_idx[e] = 0xFFFFu; }
  __syncthreads();

  // bitonic sort: key desc, idx asc (matches stable lax.top_k + argmax-first)
  for (int k = 2; k <= CAP; k <<= 1) {
    for (int j = k >> 1; j > 0; j >>= 1) {
      for (int t = tid; t < CAP / 2; t += 256) {
        int i = ((t & ~(j - 1)) << 1) | (t & (j - 1));
        int p = i | j;
        unsigned int ka = s_key[i], kb = s_key[p];
        unsigned short ia = s_idx[i], ib = s_idx[p];
        bool up = ((i & k) == 0);
        bool g = (ka < kb) || (ka == kb && ia > ib);  // i sorts later
        bool l = (kb < ka) || (ka == kb && ib > ia);  // i sorts earlier
        if (up ? g : l) {
          s_key[i] = kb; s_key[p] = ka;
          s_idx[i] = ib; s_idx[p] = ia;
        }
      }
      __syncthreads();
    }
  }

  // greedy NMS over sorted prefix, chunks of 512
  float4* cbox = (float4*)s_pool;  // hist no longer needed
  int L = (M < 5000) ? M : 5000;   // reference examines at most top-5000
  for (int base = 0; base < L; base += 512) {
    int cn = min(512, L - base);
    int ns0 = s_nsel;
    if (ns0 >= POSTN) break;
    for (int t = tid; t < cn; t += 256) {
      int n = s_idx[base + t];
      float4 bx = boxes[(size_t)b * NANCH + n];
      bool alive = true;
      for (int s = 0; s < ns0; s++) {
        if (iou_ref(bx, s_selbox[s]) > 0.5f) { alive = false; break; }
      }
      cbox[t] = bx;
      s_alive[t] = alive ? 1 : 0;
    }
    __syncthreads();
    for (int i = 0; i < cn; i++) {
      if (s_nsel >= POSTN) break;       // uniform (all writes barriered)
      if (!s_alive[i]) continue;        // uniform
      float4 bi = cbox[i];
      float sc = __uint_as_float(s_key[base + i]);
      if (!(iou_ref(bi, bi) > 0.5f)) {
        // degenerate (zero-area) box never self-suppresses: reference re-selects
        // it for every remaining scan step -> fill remaining slots ("sticky")
        if (tid == 0) {
          for (int p = s_nsel; p < POSTN; p++) { s_selbox[p] = bi; s_sels[p] = sc; }
          s_nsel = POSTN;
        }
        __syncthreads();
        break;
      }
      for (int t = tid; t < cn; t += 256) {
        if (t > i && s_alive[t] && iou_ref(cbox[t], bi) > 0.5f) s_alive[t] = 0;
      }
      if (tid == 0) {
        s_selbox[s_nsel] = bi;
        s_sels[s_nsel] = sc;
        s_nsel = s_nsel + 1;
      }
      __syncthreads();
    }
    __syncthreads();
    if (s_nsel >= POSTN) break;
  }
  __syncthreads();
  int ns = s_nsel;

  if (!FB) {
    // tier1 valid only if it completed 100 selections within its (<5000) prefix
    bool bad = overflow || (ns < POSTN);
    if (tid == 0) flags[bc] = bad ? 1 : 0;
    if (bad) return;
  }
  for (int p = tid; p < POSTN; p += 256) {
    float sc = 0.0f;
    float4 bx = make_float4(0.0f, 0.0f, 0.0f, 0.0f);
    if (p < ns) {
      float s0 = s_sels[p];
      if (s0 > 0.2f) { sc = s0; bx = s_selbox[p]; }  // SCORE_THR gate
    }
    sel_s[bc * POSTN + p] = sc;
    sel_b[bc * POSTN + p] = bx;
  }
}

// ---------------------- per-batch stable top-100 combine ------------------------

__global__ __launch_bounds__(256) void k_final(const float* __restrict__ sel_s,
                                               const float4* __restrict__ sel_b,
                                               float* __restrict__ out) {
  int b = blockIdx.x;
  int tid = threadIdx.x;
  __shared__ unsigned int key[9000];
  __shared__ unsigned long long wred[4];
  __shared__ unsigned int win_k[POSTN];
  __shared__ int win_e[POSTN];
  const float* ss = sel_s + (size_t)b * 9000;
  for (int e = tid; e < 9000; e += 256) key[e] = __float_as_uint(ss[e]);
  __syncthreads();
  int lane = tid & 63, wid = tid >> 6;
  for (int p = 0; p < POSTN; p++) {
    unsigned long long best = 0ull;
    for (int e = tid; e < 9000; e += 256) {
      unsigned int k = key[e];
      if (k == 0xFFFFFFFFu) continue;  // removed sentinel (scores are never -NaN)
      unsigned long long v =
          ((unsigned long long)k << 32) | (unsigned int)(16383 - e);
      if (v > best) best = v;  // max key, then min flat index (stable)
    }
    for (int d = 32; d > 0; d >>= 1) {
      unsigned long long o = __shfl_down(best, (unsigned)d, 64);
      if (o > best) best = o;
    }
    if (lane == 0) wred[wid] = best;
    __syncthreads();
    if (tid == 0) {
      unsigned long long w = wred[0];
      for (int q = 1; q < 4; q++)
        if (wred[q] > w) w = wred[q];
      int e = 16383 - (int)(w & 0x3FFFull);
      win_k[p] = (unsigned int)(w >> 32);
      win_e[p] = e;
      key[e] = 0xFFFFFFFFu;
    }
    __syncthreads();
  }
  if (tid < POSTN) {
    int p = tid;
    unsigned int k = win_k[p];
    int e = win_e[p];
    float4 bx = sel_b[(size_t)b * 9000 + e];
    ((float4*)out)[b * POSTN + p] = bx;              // out_b [8,100,4]
    out[3200 + b * POSTN + p] = __uint_as_float(k);  // out_s [8,100]
    out[4000 + b * POSTN + p] = (float)(e / 100);    // out_c [8,100]
  }
  if (tid == 0) {
    int v = 0;
    for (int p = 0; p < POSTN; p++) v += (win_k[p] != 0u) ? 1 : 0;
    out[4800 + b] = (float)v;  // valid [8]
  }
}

// ------------------------------- launcher --------------------------------------

extern "C" void kernel_launch(void* const* d_in, const int* in_sizes, int n_in,
                              void* d_out, int out_size, void* d_ws, size_t ws_size,
                              hipStream_t stream) {
  const float* deltas = (const float*)d_in[0];   // [8,49104,4]
  const float* logits = (const float*)d_in[1];   // [8,49104,90]
  float* out = (float*)d_out;                    // 3200 + 800 + 800 + 8 floats
  char* ws = (char*)d_ws;

  size_t off = 0;
  auto take = [&](size_t bytes) -> char* {
    char* p = ws + off;
    off += (bytes + 255) & ~(size_t)255;
    return p;
  };
  float4* anchors = (float4*)take((size_t)NANCH * 16);
  float4* boxes = (float4*)take((size_t)NB * NANCH * 16);
  float* sel_s = (float*)take((size_t)NBC * POSTN * 4);
  float4* sel_b = (float4*)take((size_t)NBC * POSTN * 16);
  int* flags = (int*)take((size_t)NBC * 4);
  float* sT = (float*)take((size_t)NB * NC * NANCH * 4);
  int use_T = (ws_size >= off) ? 1 : 0;  // fall back to strided logit reads if ws small

  k_anchors<<<dim3((NANCH + 255) / 256), dim3(256), 0, stream>>>(anchors);
  k_decode<<<dim3((NB * NANCH + 255) / 256), dim3(256), 0, stream>>>(
      (const float4*)deltas, anchors, boxes);
  if (use_T) {
    k_trans<<<dim3((NANCH + 63) / 64, NB), dim3(256), 0, stream>>>(logits, sT);
  }
  k_nms<2048, 1536, false><<<dim3(NBC), dim3(256), 0, stream>>>(
      sT, logits, boxes, sel_s, sel_b, flags, use_T);
  k_nms<8192, 5000, true><<<dim3(NBC), dim3(256), 0, stream>>>(
      sT, logits, boxes, sel_s, sel_b, flags, use_T);
  k_final<<<dim3(NB), dim3(256), 0, stream>>>(sel_s, sel_b, out);
}